// Round 1
// baseline (538.462 us; speedup 1.0000x reference)
//
#include <hip/hip_runtime.h>

#define NN 100000
#define FIN 128
#define HC 16

// ---------------- utility ----------------
__global__ void zero_kernel(float* __restrict__ p, int n4) {
    int i = blockIdx.x * blockDim.x + threadIdx.x;
    if (i < n4) ((float4*)p)[i] = make_float4(0.f, 0.f, 0.f, 0.f);
}

// deg[dst] += 1 for every real edge (self-loops handled analytically later)
__global__ void degree_kernel(const int* __restrict__ dst, float* __restrict__ deg, int E) {
    int i = blockIdx.x * blockDim.x + threadIdx.x;
    if (i < E) atomicAdd(&deg[dst[i]], 1.0f);
}

// dis[i] = rsqrt(deg_with_selfloop)
__global__ void dis_kernel(const float* __restrict__ deg, float* __restrict__ dis, int n) {
    int i = blockIdx.x * blockDim.x + threadIdx.x;
    if (i < n) dis[i] = rsqrtf(deg[i] + 1.0f);
}

// hs[i][c] = (x[i] @ W1)[c] * dis[i]   (pre-scaled by source norm)
__global__ void h1_matmul_kernel(const float* __restrict__ x, const float* __restrict__ W1,
                                 const float* __restrict__ dis, float* __restrict__ hs, int n) {
    __shared__ float W1s[FIN * HC];
    int tid = threadIdx.x;
    for (int i = tid; i < FIN * HC; i += 256) W1s[i] = W1[i];
    __syncthreads();
    int row = blockIdx.x * 16 + (tid >> 4);
    int col = tid & 15;
    if (row >= n) return;
    const float4* xr = (const float4*)(x + (size_t)row * FIN);
    float acc = 0.f;
#pragma unroll
    for (int k4 = 0; k4 < FIN / 4; ++k4) {
        float4 v = xr[k4];
        acc += v.x * W1s[(k4 * 4 + 0) * HC + col];
        acc += v.y * W1s[(k4 * 4 + 1) * HC + col];
        acc += v.z * W1s[(k4 * 4 + 2) * HC + col];
        acc += v.w * W1s[(k4 * 4 + 3) * HC + col];
    }
    hs[row * HC + col] = acc * dis[row];
}

// agg1[dst][c] += hs[src][c] — 16 threads per edge, fully coalesced 64B gather/scatter
__global__ void agg1_kernel(const int* __restrict__ src, const int* __restrict__ dst,
                            const float* __restrict__ hs, float* __restrict__ agg1, int E) {
    int g = blockIdx.x * blockDim.x + threadIdx.x;
    int e = g >> 4;
    if (e >= E) return;
    int c = g & 15;
    int s = src[e], d = dst[e];
    atomicAdd(&agg1[d * HC + c], hs[s * HC + c]);
}

// h1 = relu(dis*(agg1 + hs) + b1);  h2s = (h1 @ W2) * dis
__global__ void layer1_finish_kernel(const float* __restrict__ agg1, const float* __restrict__ hs,
                                     const float* __restrict__ dis, const float* __restrict__ b1,
                                     const float* __restrict__ W2, float* __restrict__ h2s, int n) {
    int i = blockIdx.x * blockDim.x + threadIdx.x;
    if (i >= n) return;
    float d = dis[i];
    const float4* a4 = (const float4*)(agg1 + (size_t)i * HC);
    const float4* s4 = (const float4*)(hs + (size_t)i * HC);
    float acc = 0.f;
#pragma unroll
    for (int q = 0; q < HC / 4; ++q) {
        float4 a = a4[q];
        float4 s = s4[q];
        float v0 = fmaxf(d * (a.x + s.x) + b1[q * 4 + 0], 0.f);
        float v1 = fmaxf(d * (a.y + s.y) + b1[q * 4 + 1], 0.f);
        float v2 = fmaxf(d * (a.z + s.z) + b1[q * 4 + 2], 0.f);
        float v3 = fmaxf(d * (a.w + s.w) + b1[q * 4 + 3], 0.f);
        acc += v0 * W2[q * 4 + 0] + v1 * W2[q * 4 + 1] + v2 * W2[q * 4 + 2] + v3 * W2[q * 4 + 3];
    }
    h2s[i] = acc * d;
}

// agg2[dst] += h2s[src] — 1 atomic per edge
__global__ void agg2_kernel(const int* __restrict__ src, const int* __restrict__ dst,
                            const float* __restrict__ h2s, float* __restrict__ agg2, int E) {
    int e = blockIdx.x * blockDim.x + threadIdx.x;
    if (e < E) atomicAdd(&agg2[dst[e]], h2s[src[e]]);
}

// out[i] = dis[i]*(agg2[i] + h2s[i]) + b2
__global__ void out_kernel(const float* __restrict__ agg2, const float* __restrict__ h2s,
                           const float* __restrict__ dis, const float* __restrict__ b2,
                           float* __restrict__ out, int n) {
    int i = blockIdx.x * blockDim.x + threadIdx.x;
    if (i < n) out[i] = dis[i] * (agg2[i] + h2s[i]) + b2[0];
}

extern "C" void kernel_launch(void* const* d_in, const int* in_sizes, int n_in,
                              void* d_out, int out_size, void* d_ws, size_t ws_size,
                              hipStream_t stream) {
    const float* x  = (const float*)d_in[0];
    const int* ei   = (const int*)d_in[1];
    const float* W1 = (const float*)d_in[2];
    const float* b1 = (const float*)d_in[3];
    const float* W2 = (const float*)d_in[4];
    const float* b2 = (const float*)d_in[5];
    float* out = (float*)d_out;

    const int n = in_sizes[0] / FIN;   // 100000
    const int E = in_sizes[1] / 2;     // 3200000
    const int* src = ei;
    const int* dst = ei + E;

    float* ws   = (float*)d_ws;
    // zeroed region first (deg + agg1 + agg2 contiguous = 18n floats)
    float* deg  = ws;                // n
    float* agg1 = ws + n;            // 16n
    float* agg2 = ws + 17 * n;       // n
    float* dis  = ws + 18 * n;       // n
    float* hs   = ws + 19 * n;       // 16n
    float* h2s  = ws + 35 * n;       // n   (total 36n floats = 14.4 MB)

    int zero4 = (18 * n) / 4;        // 18n divisible by 4 (n=100000)
    zero_kernel<<<(zero4 + 255) / 256, 256, 0, stream>>>(ws, zero4);

    degree_kernel<<<(E + 255) / 256, 256, 0, stream>>>(dst, deg, E);
    dis_kernel<<<(n + 255) / 256, 256, 0, stream>>>(deg, dis, n);
    h1_matmul_kernel<<<(n + 15) / 16, 256, 0, stream>>>(x, W1, dis, hs, n);

    long long tot1 = (long long)E * HC;
    agg1_kernel<<<(int)((tot1 + 255) / 256), 256, 0, stream>>>(src, dst, hs, agg1, E);

    layer1_finish_kernel<<<(n + 255) / 256, 256, 0, stream>>>(agg1, hs, dis, b1, W2, h2s, n);
    agg2_kernel<<<(E + 255) / 256, 256, 0, stream>>>(src, dst, h2s, agg2, E);
    out_kernel<<<(n + 255) / 256, 256, 0, stream>>>(agg2, h2s, dis, b2, out, n);
}

// Round 2
// 342.925 us; speedup vs baseline: 1.5702x; 1.5702x over previous
//
#include <hip/hip_runtime.h>

#define FIN 128
#define HC 16

// ---------------- utility ----------------
__global__ void zero_kernel(int* __restrict__ p, int n) {
    int i = blockIdx.x * blockDim.x + threadIdx.x;
    if (i < n) p[i] = 0;
}

// ONE atomic pass: degree histogram AND per-edge rank within its dst bucket.
__global__ void hist_rank_kernel(const int* __restrict__ dst, int* __restrict__ cnt,
                                 int* __restrict__ rank, int E) {
    int e = blockIdx.x * blockDim.x + threadIdx.x;
    if (e < E) rank[e] = atomicAdd(&cnt[dst[e]], 1);
}

// ---- 3-phase exclusive scan of cnt[n] -> offs[n], fused dis = rsqrt(deg+1) ----
__global__ void scan_bsum_kernel(const int* __restrict__ cnt, int* __restrict__ bsum, int n) {
    __shared__ int s[256];
    int t = threadIdx.x;
    int i = blockIdx.x * 256 + t;
    s[t] = (i < n) ? cnt[i] : 0;
    __syncthreads();
    for (int off = 128; off > 0; off >>= 1) {
        if (t < off) s[t] += s[t + off];
        __syncthreads();
    }
    if (t == 0) bsum[blockIdx.x] = s[0];
}

// single block, 512 threads: exclusive scan of bsum[nb] (nb <= 512)
__global__ void scan_top_kernel(const int* __restrict__ bsum, int* __restrict__ bsumEx, int nb) {
    __shared__ int s[512];
    int t = threadIdx.x;
    s[t] = (t < nb) ? bsum[t] : 0;
    __syncthreads();
    for (int off = 1; off < 512; off <<= 1) {
        int v = (t >= off) ? s[t - off] : 0;
        __syncthreads();
        s[t] += v;
        __syncthreads();
    }
    if (t < nb) bsumEx[t] = s[t] - bsum[t];  // exclusive
}

__global__ void scan_final_kernel(const int* __restrict__ cnt, const int* __restrict__ bsumEx,
                                  int* __restrict__ offs, float* __restrict__ dis, int n) {
    __shared__ int s[256];
    int t = threadIdx.x;
    int i = blockIdx.x * 256 + t;
    int v = (i < n) ? cnt[i] : 0;
    s[t] = v;
    __syncthreads();
    for (int off = 1; off < 256; off <<= 1) {
        int u = (t >= off) ? s[t - off] : 0;
        __syncthreads();
        s[t] += u;
        __syncthreads();
    }
    if (i < n) {
        offs[i] = bsumEx[blockIdx.x] + s[t] - v;  // exclusive scan
        dis[i] = rsqrtf((float)v + 1.0f);         // +1 self-loop
    }
}

// scatter edges into CSR slots — plain writes, no atomics
__global__ void scatter_kernel(const int* __restrict__ src, const int* __restrict__ dst,
                               const int* __restrict__ rank, const int* __restrict__ offs,
                               int* __restrict__ csr, int E) {
    int e = blockIdx.x * blockDim.x + threadIdx.x;
    if (e < E) csr[offs[dst[e]] + rank[e]] = src[e];
}

// hs[i][c] = (x[i] @ W1)[c] * dis[i]
__global__ void h1_matmul_kernel(const float* __restrict__ x, const float* __restrict__ W1,
                                 const float* __restrict__ dis, float* __restrict__ hs, int n) {
    __shared__ float W1s[FIN * HC];
    int tid = threadIdx.x;
    for (int i = tid; i < FIN * HC; i += 256) W1s[i] = W1[i];
    __syncthreads();
    int row = blockIdx.x * 16 + (tid >> 4);
    int col = tid & 15;
    if (row >= n) return;
    const float4* xr = (const float4*)(x + (size_t)row * FIN);
    float acc = 0.f;
#pragma unroll
    for (int k4 = 0; k4 < FIN / 4; ++k4) {
        float4 v = xr[k4];
        acc += v.x * W1s[(k4 * 4 + 0) * HC + col];
        acc += v.y * W1s[(k4 * 4 + 1) * HC + col];
        acc += v.z * W1s[(k4 * 4 + 2) * HC + col];
        acc += v.w * W1s[(k4 * 4 + 3) * HC + col];
    }
    hs[row * HC + col] = acc * dis[row];
}

// pull layer1: quarter-wave (16 lanes = 16 channels) per node.
// A = sum_{j in N(i)} hs[j]; h1 = relu(dis*(A + hs_i) + b1); h2s = (h1@W2)*dis
__global__ void pull_layer1_kernel(const int* __restrict__ offs, const int* __restrict__ cnt,
                                   const int* __restrict__ csr, const float* __restrict__ hs,
                                   const float* __restrict__ dis, const float* __restrict__ b1,
                                   const float* __restrict__ W2, float* __restrict__ h2s, int n) {
    int g = blockIdx.x * blockDim.x + threadIdx.x;
    int node = g >> 4;
    int c = g & 15;
    if (node >= n) return;
    int start = offs[node];
    int m = cnt[node];
    float a = 0.f;
    for (int k = 0; k < m; ++k) {
        int s = csr[start + k];           // broadcast within quarter-wave
        a += hs[s * HC + c];              // 64B coalesced gather
    }
    float d = dis[node];
    float h1 = fmaxf(d * (a + hs[node * HC + c]) + b1[c], 0.f);
    float v = h1 * W2[c];
    v += __shfl_xor(v, 1);
    v += __shfl_xor(v, 2);
    v += __shfl_xor(v, 4);
    v += __shfl_xor(v, 8);
    if (c == 0) h2s[node] = v * d;
}

// pull layer2 + epilogue: out_i = dis_i*(sum h2s[j] + h2s_i) + b2
__global__ void pull_layer2_kernel(const int* __restrict__ offs, const int* __restrict__ cnt,
                                   const int* __restrict__ csr, const float* __restrict__ h2s,
                                   const float* __restrict__ dis, const float* __restrict__ b2,
                                   float* __restrict__ out, int n) {
    int i = blockIdx.x * blockDim.x + threadIdx.x;
    if (i >= n) return;
    int start = offs[i];
    int m = cnt[i];
    float a = 0.f;
    for (int k = 0; k < m; ++k) a += h2s[csr[start + k]];
    out[i] = dis[i] * (a + h2s[i]) + b2[0];
}

extern "C" void kernel_launch(void* const* d_in, const int* in_sizes, int n_in,
                              void* d_out, int out_size, void* d_ws, size_t ws_size,
                              hipStream_t stream) {
    const float* x  = (const float*)d_in[0];
    const int* ei   = (const int*)d_in[1];
    const float* W1 = (const float*)d_in[2];
    const float* b1 = (const float*)d_in[3];
    const float* W2 = (const float*)d_in[4];
    const float* b2 = (const float*)d_in[5];
    float* out = (float*)d_out;

    const int n = in_sizes[0] / FIN;   // 100000
    const int E = in_sizes[1] / 2;     // 3200000
    const int* src = ei;
    const int* dst = ei + E;

    // workspace layout (ints then floats), ~33.6 MB total
    int* cnt    = (int*)d_ws;             // n      (zeroed)
    int* rank   = cnt + n;                // E
    int* csr    = rank + E;               // E
    int* offs   = csr + E;                // n
    int* bsum   = offs + n;               // 512
    int* bsumEx = bsum + 512;             // 512
    float* dis  = (float*)(bsumEx + 512); // n
    float* hs   = dis + n;                // 16n
    float* h2s  = hs + 16 * n;            // n

    const int nb = (n + 255) / 256;       // 391 blocks for node-sized arrays

    zero_kernel<<<nb, 256, 0, stream>>>(cnt, n);
    hist_rank_kernel<<<(E + 255) / 256, 256, 0, stream>>>(dst, cnt, rank, E);

    scan_bsum_kernel<<<nb, 256, 0, stream>>>(cnt, bsum, n);
    scan_top_kernel<<<1, 512, 0, stream>>>(bsum, bsumEx, nb);
    scan_final_kernel<<<nb, 256, 0, stream>>>(cnt, bsumEx, offs, dis, n);

    scatter_kernel<<<(E + 255) / 256, 256, 0, stream>>>(src, dst, rank, offs, csr, E);

    h1_matmul_kernel<<<(n + 15) / 16, 256, 0, stream>>>(x, W1, dis, hs, n);

    pull_layer1_kernel<<<(n * 16 + 255) / 256, 256, 0, stream>>>(offs, cnt, csr, hs, dis, b1, W2, h2s, n);
    pull_layer2_kernel<<<nb, 256, 0, stream>>>(offs, cnt, csr, h2s, dis, b2, out, n);
}